// Round 1
// 2938.541 us; speedup vs baseline: 1.1788x; 1.1788x over previous
//
#include <hip/hip_runtime.h>
#include <math.h>

#define Bn 2048
#define Cn 256
#define Tn 512
#define VTHf 3.0f

// ---------------------------------------------------------------------------
// Transpose: dst[j][c] = src[c][j]. If blockIdx.x == zrow, write a zero row
// (used to give WrT a 257th all-zeros row so "no spike" is row Cn).
// ---------------------------------------------------------------------------
__global__ void transpose_kernel(const float* __restrict__ src,
                                 float* __restrict__ dst, int zrow)
{
    if ((int)blockIdx.x == zrow) {
        dst[(size_t)blockIdx.x * Cn + threadIdx.x] = 0.f;
        return;
    }
    dst[(size_t)blockIdx.x * Cn + threadIdx.x] =
        src[(size_t)threadIdx.x * Cn + blockIdx.x];
}

// ---------------------------------------------------------------------------
// GEMM: Y[b, t - t0, c] = sum_k x[b, k, t] * Wf[c, k]  for t in [t0, t0+Tc)
// 128t x 128c tile, BK=16, 256 threads, 8x8 micro-tile.
// Uses WfT (pre-transposed Wf) so both LDS stages are coalesced row writes.
// K accumulation order identical to the 4x4 version -> bit-exact Y.
// ---------------------------------------------------------------------------
__global__ __launch_bounds__(256, 4) void gemm_kernel(
    const float* __restrict__ x, const float* __restrict__ WfT,
    float* __restrict__ Y, int t0, int Tc)
{
    const int nTt = Tc >> 7;
    const int tt  = blockIdx.x % nTt;
    const int cc  = blockIdx.x / nTt;   // 0..1
    const int b   = blockIdx.y;
    const int tbase = t0 + tt * 128;
    const int cbase = cc * 128;

    __shared__ float As[16][132];   // [k][t], +4 pad: write aliasing 2-way (free)
    __shared__ float Ws[16][132];   // [k][c]

    const int tid = threadIdx.x;
    const int tx  = tid & 15;       // c micro group (8 c)
    const int ty  = tid >> 4;       // t micro group (8 t)

    const int sk = tid >> 4;        // staging row 0..15
    const int st = (tid & 15) * 8;  // staging col offset

    float acc[8][8];
    #pragma unroll
    for (int i = 0; i < 8; ++i)
        #pragma unroll
        for (int j = 0; j < 8; ++j) acc[i][j] = 0.f;

    const float* xp = x + (size_t)b * Cn * Tn + tbase + st;
    const float* wp = WfT + cbase + st;

    for (int k0 = 0; k0 < Cn; k0 += 16) {
        const float* xs = xp + (size_t)(k0 + sk) * Tn;
        const float4 a0 = *(const float4*)(xs);
        const float4 a1 = *(const float4*)(xs + 4);
        const float* wsrc = wp + (size_t)(k0 + sk) * Cn;
        const float4 w0 = *(const float4*)(wsrc);
        const float4 w1 = *(const float4*)(wsrc + 4);

        __syncthreads();            // previous tile's reads done
        *(float4*)&As[sk][st]     = a0;
        *(float4*)&As[sk][st + 4] = a1;
        *(float4*)&Ws[sk][st]     = w0;
        *(float4*)&Ws[sk][st + 4] = w1;
        __syncthreads();

        #pragma unroll
        for (int kk = 0; kk < 16; ++kk) {
            float a[8], w[8];
            *(float4*)&a[0] = *(const float4*)&As[kk][ty * 8];
            *(float4*)&a[4] = *(const float4*)&As[kk][ty * 8 + 4];
            *(float4*)&w[0] = *(const float4*)&Ws[kk][tx * 8];
            *(float4*)&w[4] = *(const float4*)&Ws[kk][tx * 8 + 4];
            #pragma unroll
            for (int i = 0; i < 8; ++i)
                #pragma unroll
                for (int j = 0; j < 8; ++j)
                    acc[i][j] = fmaf(a[i], w[j], acc[i][j]);
        }
    }

    float* Yb = Y + ((size_t)b * Tc + (size_t)(tbase - t0 + ty * 8)) * Cn
                  + cbase + tx * 8;
    #pragma unroll
    for (int i = 0; i < 8; ++i) {
        float4 o0 = make_float4(acc[i][0], acc[i][1], acc[i][2], acc[i][3]);
        float4 o1 = make_float4(acc[i][4], acc[i][5], acc[i][6], acc[i][7]);
        *(float4*)&Yb[(size_t)i * Cn]     = o0;
        *(float4*)&Yb[(size_t)i * Cn + 4] = o1;
    }
}

// ---------------------------------------------------------------------------
// Fallback GEMM for Tc==64 chunks (previous 64x64 / 4x4 kernel, unchanged).
// ---------------------------------------------------------------------------
__global__ __launch_bounds__(256) void gemm_kernel64(
    const float* __restrict__ x, const float* __restrict__ Wf,
    float* __restrict__ Y, int t0, int Tc)
{
    const int nTt  = Tc >> 6;
    const int tt   = blockIdx.x % nTt;
    const int cc   = blockIdx.x / nTt;
    const int b    = blockIdx.y;
    const int tbase = t0 + tt * 64;
    const int cbase = cc * 64;

    __shared__ float As[16][64];
    __shared__ float Ws[16][68];

    const int tid = threadIdx.x;
    const int tx  = tid & 15;
    const int ty  = tid >> 4;

    float acc[4][4];
    #pragma unroll
    for (int i = 0; i < 4; ++i)
        #pragma unroll
        for (int j = 0; j < 4; ++j) acc[i][j] = 0.f;

    const float* xb = x + (size_t)b * Cn * Tn;

    const int lt = tid & 63;
    const int lk = tid >> 6;
    const int wk = tid & 15;
    const int wc = tid >> 4;

    for (int k0 = 0; k0 < Cn; k0 += 16) {
        #pragma unroll
        for (int p = 0; p < 4; ++p)
            As[lk + 4 * p][lt] = xb[(size_t)(k0 + lk + 4 * p) * Tn + tbase + lt];
        #pragma unroll
        for (int p = 0; p < 4; ++p)
            Ws[wk][wc + 16 * p] = Wf[(size_t)(cbase + wc + 16 * p) * Cn + k0 + wk];
        __syncthreads();

        #pragma unroll
        for (int kk = 0; kk < 16; ++kk) {
            const float4 a4 = *(const float4*)&As[kk][ty * 4];
            const float4 w4 = *(const float4*)&Ws[kk][tx * 4];
            const float a[4] = {a4.x, a4.y, a4.z, a4.w};
            const float w[4] = {w4.x, w4.y, w4.z, w4.w};
            #pragma unroll
            for (int i = 0; i < 4; ++i)
                #pragma unroll
                for (int j = 0; j < 4; ++j)
                    acc[i][j] = fmaf(a[i], w[j], acc[i][j]);
        }
        __syncthreads();
    }

    float* Yb = Y + ((size_t)b * Tc + (size_t)(tbase - t0)) * Cn + cbase;
    #pragma unroll
    for (int i = 0; i < 4; ++i) {
        float4 o = make_float4(acc[i][0], acc[i][1], acc[i][2], acc[i][3]);
        *(float4*)&Yb[(size_t)(ty * 4 + i) * Cn + tx * 4] = o;
    }
}

// ---------------------------------------------------------------------------
// DPP-based max step: x = max(x, x from lane permuted by CTRL).
// CTRLs: 0xB1 quad_perm(1,0,3,2)=xor1, 0x4E quad_perm(2,3,0,1)=xor2,
//        0x141 row_half_mirror (pairs across quads in 8-group),
//        0x140 row_mirror (pairs across 8-groups in 16-row).
// ---------------------------------------------------------------------------
template <int CTRL>
__device__ __forceinline__ float fmax_dpp(float x)
{
    int xi = __builtin_bit_cast(int, x);
    int yi = __builtin_amdgcn_update_dpp(0, xi, CTRL, 0xF, 0xF, true);
    return fmaxf(x, __builtin_bit_cast(float, yi));
}

// ---------------------------------------------------------------------------
// Sequential LIF/WTA scan, one wave per batch row, 4 channels per lane.
// Wave-max via DPP (4 VALU steps) + 1 ds_swizzle (xor16) + permlane32_swap;
// argmax index via ballot + readlane (lowest lane = first argmax).
// Branchless recurrence: WrT row Cn is all zeros ("no spike").
// ---------------------------------------------------------------------------
__global__ __launch_bounds__(256) void scan_kernel(
    const float* __restrict__ Y, const float* __restrict__ WrT,
    float* __restrict__ vstate, int* __restrict__ jstate,
    float* __restrict__ out, int t0, int t1, int Tc)
{
    const int wave = threadIdx.x >> 6;
    const int lane = threadIdx.x & 63;
    const int b    = blockIdx.x * 4 + wave;
    const int c0   = lane * 4;

    const float DECAY = (float)(1.0 - 1.0 / 6.0);

    float4 v;
    int jf;
    if (t0 == 0) {
        v = make_float4(0.f, 0.f, 0.f, 0.f);
        jf = Cn;                    // zero row: no recurrent input
    } else {
        v  = *(const float4*)&vstate[(size_t)b * Cn + c0];
        jf = jstate[b];
    }

    const int nT = t1 - t0;
    const float4* Yb = (const float4*)(Y + (size_t)b * Tc * Cn) + lane;

    float4 y0 = Yb[0];
    float4 y1 = Yb[(size_t)(nT > 1 ? 1 : 0) * 64];
    float4 r  = *((const float4*)(WrT + (size_t)jf * Cn) + lane);
    float4 pv = v;

    for (int t = 0; t < nT; ++t) {
        // prefetch Y two steps ahead (clamped; duplicate loads are harmless)
        const int pf = (t + 2 < nT) ? (t + 2) : (nT - 1);
        float4 y2 = Yb[(size_t)pf * 64];

        float4 inp;
        inp.x = y0.x + r.x;
        inp.y = y0.y + r.y;
        inp.z = y0.z + r.z;
        inp.w = y0.w + r.w;

        // match reference rounding: (v * decay) then (+ inp), no contraction
        v.x = __fadd_rn(__fmul_rn(v.x, DECAY), inp.x);
        v.y = __fadd_rn(__fmul_rn(v.y, DECAY), inp.y);
        v.z = __fadd_rn(__fmul_rn(v.z, DECAY), inp.z);
        v.w = __fadd_rn(__fmul_rn(v.w, DECAY), inp.w);

        // local first-argmax over the 4 owned channels (strict > keeps lowest)
        float mv = v.x; int mi = c0;
        if (v.y > mv) { mv = v.y; mi = c0 + 1; }
        if (v.z > mv) { mv = v.z; mi = c0 + 2; }
        if (v.w > mv) { mv = v.w; mi = c0 + 3; }

        // wave-wide max, value only
        float g = mv;
        g = fmax_dpp<0xB1>(g);                       // xor 1
        g = fmax_dpp<0x4E>(g);                       // xor 2
        g = fmax_dpp<0x141>(g);                      // 8-group
        g = fmax_dpp<0x140>(g);                      // 16-group
        {
            int gi = __builtin_amdgcn_ds_swizzle(
                __builtin_bit_cast(int, g), 0x401F); // xor 16 (within 32)
            g = fmaxf(g, __builtin_bit_cast(float, gi));
        }
        {
            float ga = g, gb = g;
            asm("v_permlane32_swap_b32 %0, %1" : "+v"(ga), "+v"(gb));
            g = fmaxf(ga, gb);                       // cross-32 halves
        }

        // first lane whose local max equals the global max -> first argmax
        unsigned long long ball = __ballot(mv == g);
        int first = __ffsll(ball) - 1;
        int jr = __builtin_amdgcn_readlane(mi, first);
        int jsel = (g >= VTHf) ? jr : Cn;
        jf = __builtin_amdgcn_readfirstlane(jsel);   // pin to SGPR

        pv = v;  // pre-reset membrane potential
        if (v.x >= VTHf) v.x = 0.f;
        if (v.y >= VTHf) v.y = 0.f;
        if (v.z >= VTHf) v.z = 0.f;
        if (v.w >= VTHf) v.w = 0.f;

        // recurrent row for the NEXT step (row Cn is zeros when no spike)
        r = *((const float4*)(WrT + (size_t)jf * Cn) + lane);

        y0 = y1; y1 = y2;
    }

    if (t1 == Tn) {
        float4 o = make_float4(expf(pv.x), expf(pv.y), expf(pv.z), expf(pv.w));
        *(float4*)&out[(size_t)b * Cn + c0] = o;
    } else {
        *(float4*)&vstate[(size_t)b * Cn + c0] = v;
        if (lane == 0) jstate[b] = jf;
    }
}

// ---------------------------------------------------------------------------
extern "C" void kernel_launch(void* const* d_in, const int* in_sizes, int n_in,
                              void* d_out, int out_size, void* d_ws, size_t ws_size,
                              hipStream_t stream)
{
    const float* x  = (const float*)d_in[0];
    const float* Wf = (const float*)d_in[1];
    const float* Wr = (const float*)d_in[2];
    float* out = (float*)d_out;

    char* ws = (char*)d_ws;
    size_t off = 0;
    float* WrT = (float*)(ws + off); off += (size_t)(Cn + 1) * Cn * 4;  // +zero row
    float* WfT = (float*)(ws + off); off += (size_t)Cn * Cn * 4;
    float* vst = (float*)(ws + off); off += (size_t)Bn * Cn * 4;
    int*   jst = (int*)  (ws + off); off += (size_t)Bn * 4;
    size_t ybase = (off + 255) & ~(size_t)255;
    float* Y = (float*)(ws + ybase);
    size_t avail = ws_size > ybase ? ws_size - ybase : 0;

    // chunk T so Y fits in workspace
    int Tc = 64;
    if      ((size_t)Bn * Cn * 512 * 4 <= avail) Tc = 512;
    else if ((size_t)Bn * Cn * 256 * 4 <= avail) Tc = 256;
    else if ((size_t)Bn * Cn * 128 * 4 <= avail) Tc = 128;

    transpose_kernel<<<dim3(Cn + 1), dim3(Cn), 0, stream>>>(Wr, WrT, Cn);
    transpose_kernel<<<dim3(Cn),     dim3(Cn), 0, stream>>>(Wf, WfT, -1);

    for (int t0 = 0; t0 < Tn; t0 += Tc) {
        if (Tc >= 128) {
            dim3 g((unsigned)((Tc >> 7) * 2), (unsigned)Bn);
            gemm_kernel<<<g, 256, 0, stream>>>(x, WfT, Y, t0, Tc);
        } else {
            dim3 g((unsigned)((Tc >> 6) * 4), (unsigned)Bn);
            gemm_kernel64<<<g, 256, 0, stream>>>(x, Wf, Y, t0, Tc);
        }
        scan_kernel<<<dim3(Bn / 4), 256, 0, stream>>>(Y, WrT, vst, jst, out,
                                                      t0, t0 + Tc, Tc);
    }
}